// Round 12
// baseline (31.613 us; speedup 1.0000x reference)
//
#include <hip/hip_runtime.h>

constexpr int Bn  = 8;
constexpr int Hn  = 512;
constexpr int Wn  = 512;
constexpr int HWn = Hn * Wn;        // 262144
constexpr int NPIX = Bn * HWn;      // 2097152
constexpr int NBLK = 4096;          // 4 waves/block; wave = quarter-row, 2 px/lane
constexpr float BIGE = 1e30f;       // missing neighbor: vote==0 exactly in f32 logs

typedef float f2 __attribute__((ext_vector_type(2)));
typedef int   i2 __attribute__((ext_vector_type(2)));
typedef float f4 __attribute__((ext_vector_type(4)));

// channel order: [down_right, down, down_left, right, left, up_right, up, up_left]
// conn_t[i][r,c] = t[r,c]*t[r-dy_i,c-dx_i]; vote[i][r,c] = p_i[r,c]*p_{7-i}[r-dy_i,c-dx_i]
// dy = {1,1,1,0,0,-1,-1,-1}, dx = {1,0,-1,1,-1,1,0,-1}

__device__ __forceinline__ f2 shrf(f2 v, float edge, int lane) {   // value at col c-1
    float u = __shfl_up(v.y, 1, 64);
    if (lane == 0) u = edge;
    return (f2){u, v.x};
}
__device__ __forceinline__ f2 shlf(f2 v, float edge, int lane) {   // value at col c+1
    float d = __shfl_down(v.x, 1, 64);
    if (lane == 63) d = edge;
    return (f2){v.y, d};
}
__device__ __forceinline__ i2 shri(i2 v, int edge, int lane) {
    int u = __shfl_up(v.y, 1, 64);
    if (lane == 0) u = edge;
    return (i2){u, v.x};
}
__device__ __forceinline__ i2 shli(i2 v, int edge, int lane) {
    int d = __shfl_down(v.x, 1, 64);
    if (lane == 63) d = edge;
    return (i2){v.y, d};
}

__global__ __launch_bounds__(256) void connect_loss_main(
    const float* __restrict__ cm,   // (B,8,H,W) f32
    const int*   __restrict__ tg,   // (B,1,H,W) i32
    float*       __restrict__ ws)   // per-block partials ws[k*NBLK + blk]
{
    const int lane = threadIdx.x & 63;
    const int gw   = blockIdx.x * 4 + (threadIdx.x >> 6);    // quarter-row id, 0..16383
    const int q    = gw & 3;
    const int rowIdx = gw >> 2;                              // 0..4095
    const int r  = rowIdx & (Hn - 1);
    const int b  = rowIdx >> 9;
    const int w0 = q * 128;
    const int c0 = w0 + lane * 2;

    const float* cmb  = cm + (size_t)b * 8 * HWn;
    const int*   tgb  = tg + (size_t)b * HWn;
    const float* rowp = cmb + (size_t)r * Wn;
    const float* rowm = rowp - Wn;                           // valid iff hasUp
    const float* rowq = rowp + Wn;                           // valid iff hasDn
    const bool hasUp = (r > 0), hasDn = (r < Hn - 1);        // wave-uniform
    const bool hasL  = (q > 0), hasR = (q < 3);
    const int  cL = w0 - 1, cR = w0 + 128;

    // ---------- issue the ENTIRE load batch ----------
    f2 xo0 = *(const f2*)(rowp + (size_t)0 * HWn + c0);
    f2 xo1 = *(const f2*)(rowp + (size_t)1 * HWn + c0);
    f2 xo2 = *(const f2*)(rowp + (size_t)2 * HWn + c0);
    f2 xo3 = *(const f2*)(rowp + (size_t)3 * HWn + c0);
    f2 xo4 = *(const f2*)(rowp + (size_t)4 * HWn + c0);
    f2 xo5 = *(const f2*)(rowp + (size_t)5 * HWn + c0);
    f2 xo6 = *(const f2*)(rowp + (size_t)6 * HWn + c0);
    f2 xo7 = *(const f2*)(rowp + (size_t)7 * HWn + c0);

    f2 xm5 = {0,0}, xm6 = {0,0}, xm7 = {0,0};
    f2 xp0 = {0,0}, xp1 = {0,0}, xp2 = {0,0};
    i2 tm = {0,0}, tp = {0,0};
    if (hasUp) {
        xm5 = *(const f2*)(rowm + (size_t)5 * HWn + c0);
        xm6 = *(const f2*)(rowm + (size_t)6 * HWn + c0);
        xm7 = *(const f2*)(rowm + (size_t)7 * HWn + c0);
        tm  = *(const i2*)(tgb + (size_t)(r - 1) * Wn + c0);
    }
    if (hasDn) {
        xp0 = *(const f2*)(rowq + (size_t)0 * HWn + c0);
        xp1 = *(const f2*)(rowq + (size_t)1 * HWn + c0);
        xp2 = *(const f2*)(rowq + (size_t)2 * HWn + c0);
        tp  = *(const i2*)(tgb + (size_t)(r + 1) * Wn + c0);
    }
    i2 tt = *(const i2*)(tgb + (size_t)r * Wn + c0);

    // wave-uniform edge-column raw values (logits; exp applied after the pin)
    float lLt = 1e9f, lLm = 1e9f, lLp = 1e9f, lRt = 1e9f, lRm = 1e9f, lRp = 1e9f;
    int   tLt = 0, tLm = 0, tLp = 0, tRt = 0, tRm = 0, tRp = 0;
    if (hasL) {
        lLt = rowp[(size_t)4 * HWn + cL];  tLt = tgb[(size_t)r * Wn + cL];
        if (hasUp) { lLm = rowm[(size_t)7 * HWn + cL]; tLm = tgb[(size_t)(r - 1) * Wn + cL]; }
        if (hasDn) { lLp = rowq[(size_t)2 * HWn + cL]; tLp = tgb[(size_t)(r + 1) * Wn + cL]; }
    }
    if (hasR) {
        lRt = rowp[(size_t)3 * HWn + cR];  tRt = tgb[(size_t)r * Wn + cR];
        if (hasUp) { lRm = rowm[(size_t)5 * HWn + cR]; tRm = tgb[(size_t)(r - 1) * Wn + cR]; }
        if (hasDn) { lRp = rowq[(size_t)0 * HWn + cR]; tRp = tgb[(size_t)(r + 1) * Wn + cR]; }
    }

    // single pin: full-batch issue, ONE s_waitcnt, then pure compute
    asm volatile("" : "+v"(xo0), "+v"(xo1), "+v"(xo2), "+v"(xo3),
                      "+v"(xo4), "+v"(xo5), "+v"(xo6), "+v"(xo7),
                      "+v"(xm5), "+v"(xm6), "+v"(xm7),
                      "+v"(xp0), "+v"(xp1), "+v"(xp2),
                      "+v"(tt), "+v"(tm), "+v"(tp),
                      "+v"(lLt), "+v"(lLm), "+v"(lLp),
                      "+v"(lRt), "+v"(lRm), "+v"(lRp));

    // ---------- e = exp(-x) ----------
    const float eLt = hasL ? __expf(-lLt) : BIGE;
    const float eLm = (hasL && hasUp) ? __expf(-lLm) : BIGE;
    const float eLp = (hasL && hasDn) ? __expf(-lLp) : BIGE;
    const float eRt = hasR ? __expf(-lRt) : BIGE;
    const float eRm = (hasR && hasUp) ? __expf(-lRm) : BIGE;
    const float eRp = (hasR && hasDn) ? __expf(-lRp) : BIGE;

    f2 xo[8] = {xo0, xo1, xo2, xo3, xo4, xo5, xo6, xo7};
    f2 eo[8];
    #pragma unroll
    for (int ch = 0; ch < 8; ++ch)
        eo[ch] = (f2){__expf(-xo[ch][0]), __expf(-xo[ch][1])};
    f2 em5, em6, em7, ep0, ep1, ep2;
    if (hasUp) {
        em5 = (f2){__expf(-xm5[0]), __expf(-xm5[1])};
        em6 = (f2){__expf(-xm6[0]), __expf(-xm6[1])};
        em7 = (f2){__expf(-xm7[0]), __expf(-xm7[1])};
    } else em5 = em6 = em7 = (f2){BIGE, BIGE};
    if (hasDn) {
        ep0 = (f2){__expf(-xp0[0]), __expf(-xp0[1])};
        ep1 = (f2){__expf(-xp1[0]), __expf(-xp1[1])};
        ep2 = (f2){__expf(-xp2[0]), __expf(-xp2[1])};
    } else ep0 = ep1 = ep2 = (f2){BIGE, BIGE};

    // ---------- pair loop in E-space: E = e + en + e*en; vote = 1/(1+E) ----------
    f2 Emin = {3.4e38f, 3.4e38f};
    f2 Emax = {0.f, 0.f};
    int cnt[2] = {0, 0};
    float sx = 0.f;

    #define PAIR(i, ENX, TNX)                                            \
    {                                                                    \
        const f2 enx = (ENX);                                            \
        const i2 tnx = (TNX);                                            \
        _Pragma("unroll")                                                \
        for (int j = 0; j < 2; ++j) {                                    \
            const float E = __builtin_fmaf(eo[i][j], enx[j],             \
                                           eo[i][j] + enx[j]);           \
            Emin[j] = fminf(Emin[j], E);                                 \
            Emax[j] = fmaxf(Emax[j], E);                                 \
            const bool ct = (tt[j] != 0) & (tnx[j] != 0);                \
            cnt[j] += ct ? 1 : 0;                                        \
            sx += ct ? 0.f : xo[i][j];                                   \
        }                                                                \
    }
    PAIR(3, shrf(eo[4], eLt, lane), shri(tt, tLt, lane))   // ch4 @ (r, c-1)
    PAIR(4, shlf(eo[3], eRt, lane), shli(tt, tRt, lane))   // ch3 @ (r, c+1)
    PAIR(0, shrf(em7, eLm, lane),   shri(tm, tLm, lane))   // ch7 @ (r-1, c-1)
    PAIR(1, em6,                    tm)                    // ch6 @ (r-1, c)
    PAIR(2, shlf(em5, eRm, lane),   shli(tm, tRm, lane))   // ch5 @ (r-1, c+1)
    PAIR(5, shrf(ep2, eLp, lane),   shri(tp, tLp, lane))   // ch2 @ (r+1, c-1)
    PAIR(6, ep1,                    tp)                    // ch1 @ (r+1, c)
    PAIR(7, shlf(ep0, eRp, lane),   shli(tp, tRp, lane))   // ch0 @ (r+1, c+1)
    #undef PAIR

    // ---------- per-pixel tail: 3 logs per pixel ----------
    float s_logsx = sx, s_bimap = 0.f, s_edge = 0.f,
          s_inter = 0.f, s_fp = 0.f, s_t = 0.f;
    #pragma unroll
    for (int j = 0; j < 2; ++j) {
        // sum_i log p_i = -log prod_i (1+e_i)
        const float Pr = (((1.f + eo[0][j]) * (1.f + eo[1][j])) *
                          ((1.f + eo[2][j]) * (1.f + eo[3][j]))) *
                         (((1.f + eo[4][j]) * (1.f + eo[5][j])) *
                          ((1.f + eo[6][j]) * (1.f + eo[7][j])));
        s_logsx += __logf(Pr);

        const float Em = Emin[j], EM = Emax[j];
        const float vm = __builtin_amdgcn_rcpf(1.0f + Em);       // vmax
        s_bimap += __logf((tt[j] != 0) ? vm : Em * vm);          // t?log(vmax):log(1-vmax)
        const float vM = __builtin_amdgcn_rcpf(1.0f + EM);
        const bool eg = (cnt[j] > 0) & (cnt[j] < 8);
        s_edge += __logf(eg ? EM * vM : 1.0f);                   // log(1-vmin) on edge px
        s_fp    += vm;
        s_inter += (tt[j] != 0) ? vm : 0.f;
        s_t     += (float)tt[j];
    }

    // ---------- wave tree reduce, LDS combine, per-block plain store ----------
    float vals[6] = {s_logsx, s_bimap, s_edge, s_inter, s_fp, s_t};
    #pragma unroll
    for (int k = 0; k < 6; ++k) {
        float v = vals[k];
        #pragma unroll
        for (int off = 32; off > 0; off >>= 1) v += __shfl_down(v, off, 64);
        vals[k] = v;
    }
    __shared__ float bs[6];
    if (threadIdx.x < 6) bs[threadIdx.x] = 0.0f;
    __syncthreads();
    if ((threadIdx.x & 63) == 0) {
        #pragma unroll
        for (int k = 0; k < 6; ++k) atomicAdd(&bs[k], vals[k]);
    }
    __syncthreads();
    if (threadIdx.x < 6)
        ws[threadIdx.x * NBLK + blockIdx.x] = bs[threadIdx.x];
}

// single-block reduce of 6 x NBLK partials + final loss
__global__ __launch_bounds__(256) void connect_loss_reduce(
    const float* __restrict__ ws, float* __restrict__ out)
{
    float acc[6];
    #pragma unroll
    for (int k = 0; k < 6; ++k) {
        const f4* p = (const f4*)(ws + k * NBLK + threadIdx.x * 16);
        float s = 0.f;
        #pragma unroll
        for (int u = 0; u < 4; ++u) {                   // 256*16 = 4096 = NBLK
            const f4 a = p[u];
            s += (a.x + a.y) + (a.z + a.w);
        }
        acc[k] = s;
    }
    #pragma unroll
    for (int k = 0; k < 6; ++k) {
        float v = acc[k];
        #pragma unroll
        for (int off = 32; off > 0; off >>= 1) v += __shfl_down(v, off, 64);
        acc[k] = v;
    }
    __shared__ float bs[6];
    if (threadIdx.x < 6) bs[threadIdx.x] = 0.0f;
    __syncthreads();
    if ((threadIdx.x & 63) == 0) {
        #pragma unroll
        for (int k = 0; k < 6; ++k) atomicAdd(&bs[k], acc[k]);
    }
    __syncthreads();
    if (threadIdx.x == 0) {
        // bs[0] = sum(log(1+e)) + sum((1-ct)x) = -sum(conn BCE log-terms)
        const float conn_l  =  bs[0] / (float)(8 * NPIX);
        const float bimap_l = -bs[1] / (float)NPIX;
        const float edge_l  = -bs[2] / (float)NPIX;
        const float dice_l  = 1.0f - (2.0f * bs[3] + 1.0f) / (bs[4] + bs[5] + 1.0f);
        out[0] = conn_l + bimap_l + edge_l + dice_l;
    }
}

extern "C" void kernel_launch(void* const* d_in, const int* in_sizes, int n_in,
                              void* d_out, int out_size, void* d_ws, size_t ws_size,
                              hipStream_t stream) {
    const float* cm = (const float*)d_in[0];      // c_map (B,8,H,W) f32
    const int*   tg = (const int*)d_in[3];        // target (B,1,H,W) i32
    float* ws  = (float*)d_ws;                    // 6*NBLK floats (96 KB)
    float* out = (float*)d_out;

    connect_loss_main<<<NBLK, 256, 0, stream>>>(cm, tg, ws);
    connect_loss_reduce<<<1, 256, 0, stream>>>(ws, out);
}